// Round 11
// baseline (184.748 us; speedup 1.0000x reference)
//
#include <hip/hip_runtime.h>
#include <math.h>

#define Bq 8
#define Lq 16384
#define Hq 64
#define N2q 32
#define NLAYERSq 5

typedef _Float16 f16x8 __attribute__((ext_vector_type(8)));
typedef _Float16 f16x4 __attribute__((ext_vector_type(4)));
typedef float    f32x4 __attribute__((ext_vector_type(4)));

#define MFMA16F(a, b, c) __builtin_amdgcn_mfma_f32_16x16x32_f16(a, b, c, 0, 0, 0)

// ---- LDS layout for k_scan (dynamic): 49 KB ----
#define UT_OFF    0           // f16 [128 chunk][128 pos] swizzled, 32 KB
#define SS_OFF    32768       // Sf16 f16 [64][136] 17408 B; later St16 f16 [128][64] 16 KB
#define SMEM_SZ   50176

// ---- workspace layout (bytes) ----
#define WT_OFF_B   0                                   // f32 [320][32][4]
#define AT_OFF_B   163840                              // f16 [320][192][128]  (Wp ; Ktoe)
#define ET_OFF_B   (163840 + 15728640)                 // f16 [320][128][64]   (E)
#define W16_OFF_B  (163840 + 15728640 + 5242880)       // f16 [4][64][64]
#define U_OFF_B    (163840 + 15728640 + 5242880 + 32768)  // f16 [512][16384]

__device__ __forceinline__ float fast_tanh(float y) {
    float e = __expf(2.0f * y);
    return 1.0f - 2.0f * __builtin_amdgcn_rcpf(e + 1.0f);
}

// ---------------------------------------------------------------------------
// k_prep: per (layer,h) tables.
//   At [192][128]: rows 0-63 = Wp (mode-rows, A-operand of GEMM1);
//                  rows 64-191 = Ktoe[m][k] = K[m-k] (K[0]+=D), 0 above diag.
//   Et [128][64] : E-injection matrix (state -> output).
//   wT_tab [32][4]: (wT.re, wT.im, w16.re, w16.im), wT = w^128, w16 = wT^16
// ---------------------------------------------------------------------------
__global__ __launch_bounds__(256)
void k_prep(const float* __restrict__ log_dt, const float* __restrict__ log_A_real,
            const float* __restrict__ A_imag, const float* __restrict__ C_re,
            const float* __restrict__ C_im, const float* __restrict__ Dvec,
            const float* __restrict__ w_mid,
            float* __restrict__ wT_tab, _Float16* __restrict__ At,
            _Float16* __restrict__ Et, _Float16* __restrict__ W16) {
    __shared__ float Pr[129][33], Pi[129][33];
    __shared__ float cre[32], cim[32], Kv[128];
    __shared__ double sdAr[32], sdAi[32];
    const int ph = blockIdx.x;          // layer*64 + h
    const int tid = threadIdx.x;

    if (ph < 256 && tid < 64) {
        int e = ph * 64 + tid;
        W16[e] = (_Float16)w_mid[e];
    }

    if (tid < 32) {
        int n = tid;
        int pidx = ph * N2q + n;
        double dt  = exp((double)log_dt[ph]);
        double aRe = -exp((double)log_A_real[pidx]);
        double aIm = (double)A_imag[pidx];
        double dAr = aRe * dt, dAi = aIm * dt;
        sdAr[n] = dAr; sdAi[n] = dAi;
        double er  = exp(dAr);
        double wre = er * cos(dAi), wim = er * sin(dAi);
        double Er = wre - 1.0, Ei = wim;
        double inv = 1.0 / (aRe * aRe + aIm * aIm);
        double Fr = (Er * aRe + Ei * aIm) * inv;
        double Fi = (Ei * aRe - Er * aIm) * inv;
        double Cr = (double)C_re[pidx], Ci = (double)C_im[pidx];
        cre[n] = (float)(2.0 * (Cr * Fr - Ci * Fi));
        cim[n] = (float)(2.0 * (Cr * Fi + Ci * Fr));
        double qr = wre, qi = wim;
        #pragma unroll
        for (int s = 0; s < 7; s++) {
            double nr = qr * qr - qi * qi;
            qi = 2.0 * qr * qi; qr = nr;
        }
        float wTr = (float)qr, wTi = (float)qi;
        #pragma unroll
        for (int s = 0; s < 4; s++) {    // wT^16
            double nr = qr * qr - qi * qi;
            qi = 2.0 * qr * qi; qr = nr;
        }
        float* wt = wT_tab + ph * 128 + n * 4;
        wt[0] = wTr; wt[1] = wTi; wt[2] = (float)qr; wt[3] = (float)qi;
    }
    __syncthreads();

    const double TWO_PI  = 6.2831853071795864769;
    const double INV_2PI = 0.15915494309189533577;
    for (int e = tid; e < 129 * 32; e += 256) {
        int j = e >> 5, n = e & 31;
        double phd = (double)j * sdAi[n];
        double r   = fma(-TWO_PI, nearbyint(phd * INV_2PI), phd);
        float  mag = __expf((float)((double)j * sdAr[n]));
        float  rf  = (float)r;
        Pr[j][n] = mag * cosf(rf);
        Pi[j][n] = mag * sinf(rf);
    }
    __syncthreads();

    if (tid < 128) {
        int d = tid;
        float s = 0.f;
        #pragma unroll 8
        for (int n = 0; n < 32; n++)
            s += cre[n] * Pr[d][n] - cim[n] * Pi[d][n];
        if (d == 0) s += Dvec[ph];
        Kv[d] = s;
    }
    __syncthreads();

    // At: [192][128]
    _Float16* atb = At + (size_t)ph * 24576;
    for (int e = tid; e < 24576; e += 256) {
        int r = e >> 7, k = e & 127;
        float v;
        if (r < 64) {
            v = (r < 32) ? Pr[127 - k][r] : Pi[127 - k][r - 32];
        } else {
            int m = r - 64;
            v = (k <= m) ? Kv[m - k] : 0.f;
        }
        atb[e] = (_Float16)v;
    }
    // Et: [128][64]
    _Float16* etb = Et + (size_t)ph * 8192;
    for (int e = tid; e < 8192; e += 256) {
        int m = e >> 6, kk = e & 63;
        int n2 = kk & 31;
        float pr = Pr[m + 1][n2], pi2 = Pi[m + 1][n2];
        float v = (kk < 32) ? (cre[n2] * pr - cim[n2] * pi2)
                            : -(cre[n2] * pi2 + cim[n2] * pr);
        etb[e] = (_Float16)v;
    }
}

// ---------------------------------------------------------------------------
// k_scan: fp16 MFMA DSSM layer, in-place on u16[bh][16384]. Layer 0 fuses the
// input stage (dB -> linear -> tanh). 256 thr (4 waves), 49 KB LDS.
// Phases: stage -> bigGEMM([Wp;Ktoe].U) -> reg-scan -> E.S + tanh + direct
// store. 4 barriers; Y accumulators live in VGPRs across the scan.
// ---------------------------------------------------------------------------
__global__ __launch_bounds__(256, 3)
void k_scan(const float* __restrict__ x, _Float16* __restrict__ u16,
            const _Float16* __restrict__ At_all, const _Float16* __restrict__ Et_all,
            const float* __restrict__ wT_all, int layer,
            const float* __restrict__ w_in, const float* __restrict__ b_in) {
    extern __shared__ char smem[];
    char* UT = smem + UT_OFF;            // f16 [128][128] swizzled (byte rows 256)
    char* Sf = smem + SS_OFF;            // f16 [64][136]  (byte rows 272)
    char* St = smem + SS_OFF;            // f16 [128][64] swizzled (byte rows 128)

    const int bh = blockIdx.x;
    const int h  = bh & 63;
    const int tid = threadIdx.x;
    const int lane = tid & 63;
    const int wave = tid >> 6;               // 0..3
    const int ph = layer * 64 + h;
    const _Float16* At = At_all + (size_t)ph * 24576;
    const _Float16* Et = Et_all + (size_t)ph * 8192;
    const float* wT4 = wT_all + ph * 128;
    _Float16* uu = u16 + ((size_t)bh << 14);

    const int rA = lane & 15;     // fragment row/col index
    const int qA = lane >> 4;     // fragment k-group

    // ---- stage -> UT (fp16), XOR-swizzled: UT[n][k] at n*256 + (2k ^ ((n&7)<<4))
    if (layer == 0) {
        const float* xb = x + ((size_t)(bh >> 6) << 14);
        const float wi = w_in[h], bi = b_in[h];
        for (int it = 0; it < 8; ++it) {
            int flat8 = (it * 256 + tid) * 8;
            int n = flat8 >> 7, k = flat8 & 127;
            float4 a = *(const float4*)(xb + flat8);
            float4 b = *(const float4*)(xb + flat8 + 4);
            float f[8] = {a.x, a.y, a.z, a.w, b.x, b.y, b.z, b.w};
            f16x8 hv;
            #pragma unroll
            for (int j = 0; j < 8; j++) {
                float s = 6.0205999132796239f * __log2f(fabsf(f[j]) + 1e-5f);
                hv[j] = (_Float16)fast_tanh(fmaf(s, wi, bi));
            }
            *(f16x8*)(UT + n * 256 + ((k * 2) ^ ((n & 7) << 4))) = hv;
        }
    } else {
        for (int it = 0; it < 8; ++it) {
            int flat8 = (it * 256 + tid) * 8;
            int n = flat8 >> 7, k = flat8 & 127;
            f16x8 hv = *(const f16x8*)(uu + flat8);
            *(f16x8*)(UT + n * 256 + ((k * 2) ^ ((n & 7) << 4))) = hv;
        }
    }
    __syncthreads();

    // ---- bigGEMM: [Sf ; Y_toe] = [Wp ; Ktoe] . U  (per wave: 3 m-tiles) ----
    f32x4 accS[8];
    f32x4 accY[2][8];
    #pragma unroll
    for (int nt = 0; nt < 8; nt++) {
        accS[nt]    = (f32x4){0.f, 0.f, 0.f, 0.f};
        accY[0][nt] = (f32x4){0.f, 0.f, 0.f, 0.f};
        accY[1][nt] = (f32x4){0.f, 0.f, 0.f, 0.f};
    }
    for (int ks = 0; ks < 4; ks++) {
        f16x8 aS  = *(const f16x8*)(At + (wave * 16 + rA) * 128 + ks * 32 + qA * 8);
        f16x8 aY0 = *(const f16x8*)(At + (64 + (wave * 2 + 0) * 16 + rA) * 128 + ks * 32 + qA * 8);
        f16x8 aY1 = *(const f16x8*)(At + (64 + (wave * 2 + 1) * 16 + rA) * 128 + ks * 32 + qA * 8);
        #pragma unroll
        for (int nt = 0; nt < 8; nt++) {
            int n = nt * 16 + rA;
            f16x8 bv = *(const f16x8*)(UT + n * 256 + ((ks * 64 + qA * 16) ^ ((n & 7) << 4)));
            accS[nt]    = MFMA16F(aS,  bv, accS[nt]);
            accY[0][nt] = MFMA16F(aY0, bv, accY[0][nt]);
            accY[1][nt] = MFMA16F(aY1, bv, accY[1][nt]);
        }
    }
    #pragma unroll
    for (int nt = 0; nt < 8; nt++) {
        int c = nt * 16 + rA;
        #pragma unroll
        for (int r = 0; r < 4; r++)
            *(_Float16*)(Sf + (wave * 16 + qA * 4 + r) * 272 + c * 2) = (_Float16)accS[nt][r];
    }
    __syncthreads();

    // ---- cross-chunk scan: Sf16 -> registers -> St16 (fp16, swizzled) ----
    {
        const int sn = tid >> 3;        // mode 0..31
        const int ss = tid & 7;         // sub-block of 16 chunks
        const float wTr = wT4[sn * 4 + 0], wTi = wT4[sn * 4 + 1];
        float fr[16], fi[16];
        {
            f16x8 a0 = *(const f16x8*)(Sf + sn * 272 + ss * 32);
            f16x8 a1 = *(const f16x8*)(Sf + sn * 272 + ss * 32 + 16);
            f16x8 b0 = *(const f16x8*)(Sf + (sn + 32) * 272 + ss * 32);
            f16x8 b1 = *(const f16x8*)(Sf + (sn + 32) * 272 + ss * 32 + 16);
            #pragma unroll
            for (int j = 0; j < 8; j++) {
                fr[j] = (float)a0[j]; fr[j + 8] = (float)a1[j];
                fi[j] = (float)b0[j]; fi[j + 8] = (float)b1[j];
            }
        }
        float Tr = 0.f, Ti = 0.f;
        #pragma unroll
        for (int i = 0; i < 16; i++) {
            float nTr = fmaf(wTr, Tr, fmaf(-wTi, Ti, fr[i]));
            Ti = fmaf(wTr, Ti, fmaf(wTi, Tr, fi[i]));
            Tr = nTr;
        }
        float gr = wT4[sn * 4 + 2], gi = wT4[sn * 4 + 3];
        #pragma unroll
        for (int s = 0; s < 3; s++) {
            float pr = __shfl_up(Tr, 1 << s, 8);
            float pi = __shfl_up(Ti, 1 << s, 8);
            if (ss >= (1 << s)) {
                Tr = fmaf(gr, pr, fmaf(-gi, pi, Tr));
                Ti = fmaf(gr, pi, fmaf(gi, pr, Ti));
            }
            float ngr = fmaf(gr, gr, -gi * gi);
            gi = 2.f * gr * gi; gr = ngr;
        }
        float Er_ = __shfl_up(Tr, 1, 8);
        float Ei_ = __shfl_up(Ti, 1, 8);
        if (ss == 0) { Er_ = 0.f; Ei_ = 0.f; }
        __syncthreads();   // all Sf reads done; St overlays Sf
        float Gr = Er_, Gi = Ei_;
        #pragma unroll
        for (int i = 0; i < 16; i++) {
            int c = ss * 16 + i;
            int sw = (c & 7) << 4;
            *(_Float16*)(St + c * 128 + ((sn * 2) ^ sw))        = (_Float16)Gr;
            *(_Float16*)(St + c * 128 + (((sn + 32) * 2) ^ sw)) = (_Float16)Gi;
            float nGr = fmaf(wTr, Gr, fmaf(-wTi, Gi, fr[i]));
            Gi = fmaf(wTr, Gi, fmaf(wTi, Gr, fi[i]));
            Gr = nGr;
        }
    }
    __syncthreads();

    // ---- E.S (K=64) + tanh + direct f16x4 store (l = c*128 + m) ----
    #pragma unroll
    for (int mi = 0; mi < 2; mi++) {
        const _Float16* Erow = Et + ((wave * 2 + mi) * 16 + rA) * 64;
        #pragma unroll
        for (int ks2 = 0; ks2 < 2; ks2++) {
            f16x8 af = *(const f16x8*)(Erow + ks2 * 32 + qA * 8);
            #pragma unroll
            for (int nt = 0; nt < 8; nt++) {
                int c = nt * 16 + rA;
                f16x8 bv = *(const f16x8*)(St + c * 128 + ((ks2 * 64 + qA * 16) ^ ((c & 7) << 4)));
                accY[mi][nt] = MFMA16F(af, bv, accY[mi][nt]);
            }
        }
        int m0 = (wave * 2 + mi) * 16 + qA * 4;
        #pragma unroll
        for (int nt = 0; nt < 8; nt++) {
            int c = nt * 16 + rA;
            f16x4 o;
            o[0] = (_Float16)fast_tanh(accY[mi][nt][0]);
            o[1] = (_Float16)fast_tanh(accY[mi][nt][1]);
            o[2] = (_Float16)fast_tanh(accY[mi][nt][2]);
            o[3] = (_Float16)fast_tanh(accY[mi][nt][3]);
            *(f16x4*)(uu + c * 128 + m0) = o;
        }
    }
}

// ---------------------------------------------------------------------------
// k_linear: MFMA channel-mix + tanh, fp16 in-place.
// ---------------------------------------------------------------------------
__global__ __launch_bounds__(256, 4)
void k_linear(_Float16* __restrict__ uio, const _Float16* __restrict__ W16,
              const float* __restrict__ bias) {
    __shared__ __align__(16) char lmem[33792];
    _Float16* Ul  = (_Float16*)lmem;     // [256 l][64 h], row 128 B, swizzled
    _Float16* yst = (_Float16*)lmem;     // [64 o][264 l] overlay after GEMM

    const int b   = blockIdx.y;
    const int l0  = blockIdx.x * 256;
    const int tid = threadIdx.x;
    const int lane = tid & 63;
    const int wave = tid >> 6;      // m-tile 0..3
    const int rA = lane & 15;
    const int qA = lane >> 4;

    _Float16* ub = uio + ((size_t)b << 20) + l0;

    for (int it = 0; it < 4; ++it) {
        int g  = it * 256 + tid;
        int hp = g >> 5;
        int l8 = g & 31;
        f16x8 v0 = *(const f16x8*)(ub + (size_t)(hp * 2)     * Lq + l8 * 8);
        f16x8 v1 = *(const f16x8*)(ub + (size_t)(hp * 2 + 1) * Lq + l8 * 8);
        const unsigned short* p0 = (const unsigned short*)&v0;
        const unsigned short* p1 = (const unsigned short*)&v1;
        int sw = (l8 & 7) << 4;
        #pragma unroll
        for (int j = 0; j < 8; j++) {
            unsigned int pk = (unsigned int)p0[j] | ((unsigned int)p1[j] << 16);
            *(unsigned int*)((char*)Ul + (l8 * 8 + j) * 128 + ((hp * 4) ^ sw)) = pk;
        }
    }
    __syncthreads();

    f32x4 acc[16];
    #pragma unroll
    for (int nt = 0; nt < 16; nt++) acc[nt] = (f32x4){0.f, 0.f, 0.f, 0.f};
    const _Float16* Wrow = W16 + (wave * 16 + rA) * 64;
    #pragma unroll
    for (int kf = 0; kf < 2; kf++) {
        f16x8 af = *(const f16x8*)(Wrow + kf * 32 + qA * 8);
        #pragma unroll
        for (int nt = 0; nt < 16; nt++) {
            int n = nt * 16 + rA;
            int sw = ((n >> 3) & 7) << 4;
            f16x8 bv = *(const f16x8*)((char*)Ul + n * 128 + ((kf * 64 + qA * 16) ^ sw));
            acc[nt] = MFMA16F(af, bv, acc[nt]);
        }
    }
    __syncthreads();

    {
        int ob = wave * 16 + qA * 4;
        float bo0 = bias[ob], bo1 = bias[ob + 1], bo2 = bias[ob + 2], bo3 = bias[ob + 3];
        #pragma unroll
        for (int nt = 0; nt < 16; nt++) {
            int l = nt * 16 + rA;
            yst[(ob + 0) * 264 + l] = (_Float16)fast_tanh(acc[nt][0] + bo0);
            yst[(ob + 1) * 264 + l] = (_Float16)fast_tanh(acc[nt][1] + bo1);
            yst[(ob + 2) * 264 + l] = (_Float16)fast_tanh(acc[nt][2] + bo2);
            yst[(ob + 3) * 264 + l] = (_Float16)fast_tanh(acc[nt][3] + bo3);
        }
    }
    __syncthreads();
    for (int it = 0; it < 8; ++it) {
        int e = it * 256 + tid;
        int o = e >> 5, l8 = e & 31;
        f16x8 hv = *(const f16x8*)(yst + o * 264 + l8 * 8);
        *(f16x8*)(ub + (size_t)o * Lq + l8 * 8) = hv;
    }
}

// ---------------------------------------------------------------------------
// k_out: out[b,l] = x[b,l] * 10^((sum_h w_out[h]*u16[b,h,l] + b_out)/20)
// ---------------------------------------------------------------------------
__global__ __launch_bounds__(256)
void k_out(const _Float16* __restrict__ u16, const float* __restrict__ x,
           const float* __restrict__ w_out, const float* __restrict__ b_out,
           float* __restrict__ out) {
    int idx = blockIdx.x * 256 + threadIdx.x;
    int b = idx >> 14;
    int l = idx & (Lq - 1);
    const _Float16* up = u16 + ((size_t)b << 20) + l;
    float acc = 0.f;
    #pragma unroll 8
    for (int hh = 0; hh < 64; ++hh)
        acc = fmaf(w_out[hh], (float)up[(size_t)hh << 14], acc);
    float g = acc + b_out[0];
    out[idx] = x[idx] * exp2f(g * 0.16609640474436812f);
}

// ---------------------------------------------------------------------------
extern "C" void kernel_launch(void* const* d_in, const int* in_sizes, int n_in,
                              void* d_out, int out_size, void* d_ws, size_t ws_size,
                              hipStream_t stream) {
    const float* x          = (const float*)d_in[0];
    const float* w_in       = (const float*)d_in[1];
    const float* b_in       = (const float*)d_in[2];
    const float* w_mid      = (const float*)d_in[3];
    const float* b_mid      = (const float*)d_in[4];
    const float* w_out      = (const float*)d_in[5];
    const float* b_out      = (const float*)d_in[6];
    const float* log_dt     = (const float*)d_in[7];
    const float* log_A_real = (const float*)d_in[8];
    const float* A_imag     = (const float*)d_in[9];
    const float* C_re       = (const float*)d_in[10];
    const float* C_im       = (const float*)d_in[11];
    const float* Dv         = (const float*)d_in[12];

    char* ws = (char*)d_ws;
    float*     wT_tab = (float*)(ws + WT_OFF_B);
    _Float16*  At     = (_Float16*)(ws + AT_OFF_B);
    _Float16*  Et     = (_Float16*)(ws + ET_OFF_B);
    _Float16*  W16    = (_Float16*)(ws + W16_OFF_B);
    _Float16*  u16    = (_Float16*)(ws + U_OFF_B);
    float* out = (float*)d_out;

    hipFuncSetAttribute((const void*)k_scan,
                        hipFuncAttributeMaxDynamicSharedMemorySize, SMEM_SZ);

    k_prep<<<NLAYERSq * Hq, 256, 0, stream>>>(log_dt, log_A_real, A_imag,
                                              C_re, C_im, Dv, w_mid,
                                              wT_tab, At, Et, W16);
    for (int layer = 0; layer < NLAYERSq; layer++) {
        if (layer > 0)
            k_linear<<<dim3(Lq / 256, Bq), 256, 0, stream>>>(
                u16, W16 + (size_t)(layer - 1) * Hq * Hq, b_mid + (size_t)(layer - 1) * Hq);
        k_scan<<<Bq * Hq, 256, SMEM_SZ, stream>>>(x, u16, At, Et, wT_tab, layer,
                                                  w_in, b_in);
    }
    k_out<<<(Bq * Lq) / 256, 256, 0, stream>>>(u16, x, w_out, b_out, out);
}

// Round 12
// 175.727 us; speedup vs baseline: 1.0513x; 1.0513x over previous
//
#include <hip/hip_runtime.h>
#include <math.h>

#define Bq 8
#define Lq 16384
#define Hq 64
#define N2q 32
#define NLAYERSq 5

typedef _Float16 f16x8 __attribute__((ext_vector_type(8)));
typedef _Float16 f16x4 __attribute__((ext_vector_type(4)));
typedef float    f32x4 __attribute__((ext_vector_type(4)));

#define MFMA16F(a, b, c) __builtin_amdgcn_mfma_f32_16x16x32_f16(a, b, c, 0, 0, 0)

// ---- LDS layout for k_scan (dynamic): 49 KB ----
#define UT_OFF    0           // f16 [128 chunk][128 pos] swizzled, 32 KB
#define SS_OFF    32768       // Sf16 f16 [64][136] 17408 B; later St16 f16 [128][64] 16 KB
#define SMEM_SZ   50176
#define YST_OFF   0           // f16 [128][136] overlay after GEMM2 (34816 B)

// ---- workspace layout (bytes) ----
#define WT_OFF_B   0                        // f32 [320][32][4]
#define WP_OFF_B   163840                   // f16 [320][64][128]
#define A2_OFF_B   (163840 + 5242880)       // f16 [320][128][192]
#define W16_OFF_B  (163840 + 5242880 + 15728640)          // f16 [4][64][64]
#define U_OFF_B    (163840 + 5242880 + 15728640 + 32768)  // f16 [512][16384]

__device__ __forceinline__ float fast_tanh(float y) {
    float e = __expf(2.0f * y);
    return 1.0f - 2.0f * __builtin_amdgcn_rcpf(e + 1.0f);
}

// ---------------------------------------------------------------------------
// k_prep (throughput rewrite): 4 quarter-blocks per (layer,h).
// Each block recomputes the cheap P/Kv tables, then writes ONLY its quarter
// of the Wp / A2 tables with vectorized f16x8 stores.
//   Wp [64][128]  : rows kk<32 Re(w^{127-l}), kk>=32 Im(w^{127-l})
//   A2 [128][192] : cols 0..127 Toeplitz K[m-k] (K[0]+=D); cols 128..191 E
//   wT_tab [32][4]: (wT.re, wT.im, w16.re, w16.im), wT = w^128, w16 = wT^16
// ---------------------------------------------------------------------------
__global__ __launch_bounds__(256)
void k_prep(const float* __restrict__ log_dt, const float* __restrict__ log_A_real,
            const float* __restrict__ A_imag, const float* __restrict__ C_re,
            const float* __restrict__ C_im, const float* __restrict__ Dvec,
            const float* __restrict__ w_mid,
            float* __restrict__ wT_tab, _Float16* __restrict__ Wp,
            _Float16* __restrict__ A2, _Float16* __restrict__ W16) {
    __shared__ float Pr[129][33], Pi[129][33];
    __shared__ float cre[32], cim[32], Kv[128];
    __shared__ double sdAr[32], sdAi[32];
    const int ph = blockIdx.x >> 2;     // layer*64 + h
    const int qt = blockIdx.x & 3;      // quarter
    const int tid = threadIdx.x;

    if (qt == 0 && ph < 256 && tid < 64) {
        int e = ph * 64 + tid;
        W16[e] = (_Float16)w_mid[e];
    }

    if (tid < 32) {
        int n = tid;
        int pidx = ph * N2q + n;
        double dt  = exp((double)log_dt[ph]);
        double aRe = -exp((double)log_A_real[pidx]);
        double aIm = (double)A_imag[pidx];
        double dAr = aRe * dt, dAi = aIm * dt;
        sdAr[n] = dAr; sdAi[n] = dAi;
        double er  = exp(dAr);
        double wre = er * cos(dAi), wim = er * sin(dAi);
        double Er = wre - 1.0, Ei = wim;
        double inv = 1.0 / (aRe * aRe + aIm * aIm);
        double Fr = (Er * aRe + Ei * aIm) * inv;
        double Fi = (Ei * aRe - Er * aIm) * inv;
        double Cr = (double)C_re[pidx], Ci = (double)C_im[pidx];
        cre[n] = (float)(2.0 * (Cr * Fr - Ci * Fi));
        cim[n] = (float)(2.0 * (Cr * Fi + Ci * Fr));
        if (qt == 0) {
            double qr = wre, qi = wim;
            #pragma unroll
            for (int s = 0; s < 7; s++) {
                double nr = qr * qr - qi * qi;
                qi = 2.0 * qr * qi; qr = nr;
            }
            float wTr = (float)qr, wTi = (float)qi;
            #pragma unroll
            for (int s = 0; s < 4; s++) {    // wT^16
                double nr = qr * qr - qi * qi;
                qi = 2.0 * qr * qi; qr = nr;
            }
            float* wt = wT_tab + ph * 128 + n * 4;
            wt[0] = wTr; wt[1] = wTi; wt[2] = (float)qr; wt[3] = (float)qi;
        }
    }
    __syncthreads();

    const double TWO_PI  = 6.2831853071795864769;
    const double INV_2PI = 0.15915494309189533577;
    for (int e = tid; e < 129 * 32; e += 256) {
        int j = e >> 5, n = e & 31;
        double phd = (double)j * sdAi[n];
        double r   = fma(-TWO_PI, nearbyint(phd * INV_2PI), phd);
        float  mag = __expf((float)((double)j * sdAr[n]));
        float  rf  = (float)r;
        Pr[j][n] = mag * cosf(rf);
        Pi[j][n] = mag * sinf(rf);
    }
    __syncthreads();

    if (tid < 128) {
        int d = tid;
        float s = 0.f;
        #pragma unroll 8
        for (int n = 0; n < 32; n++)
            s += cre[n] * Pr[d][n] - cim[n] * Pi[d][n];
        if (d == 0) s += Dvec[ph];
        Kv[d] = s;
    }
    __syncthreads();

    // Wp quarter: rows [qt*16, qt*16+16) of 64; 16*128/8 = 256 octets
    {
        _Float16* wpb = Wp + (size_t)ph * 8192;
        int o = tid;                       // exactly 256 octets
        int kk = (qt << 4) + (o >> 4);     // mode-row
        int l0 = (o & 15) * 8;
        f16x8 v;
        #pragma unroll
        for (int j = 0; j < 8; j++) {
            int l = l0 + j;
            v[j] = (_Float16)((kk < 32) ? Pr[127 - l][kk] : Pi[127 - l][kk - 32]);
        }
        *(f16x8*)(wpb + kk * 128 + l0) = v;
    }
    // A2 quarter: rows [qt*32, qt*32+32) of 128; 32*192/8 = 768 octets
    {
        _Float16* a2b = A2 + (size_t)ph * 24576;
        for (int o = tid; o < 768; o += 256) {
            int m  = (qt << 5) + (o / 24);     // 24 octets per row (192/8)
            int k0 = (o % 24) * 8;
            f16x8 v;
            #pragma unroll
            for (int j = 0; j < 8; j++) {
                int k = k0 + j;
                float f;
                if (k < 128) {
                    f = (k <= m) ? Kv[m - k] : 0.f;
                } else {
                    int kk = k - 128, n2 = kk & 31;
                    float pr = Pr[m + 1][n2], pi2 = Pi[m + 1][n2];
                    f = (kk < 32) ? (cre[n2] * pr - cim[n2] * pi2)
                                  : -(cre[n2] * pi2 + cim[n2] * pr);
                }
                v[j] = (_Float16)f;
            }
            *(f16x8*)(a2b + m * 192 + k0) = v;
        }
    }
}

// ---------------------------------------------------------------------------
// k_scan: fp16 MFMA DSSM layer, in-place on u16[bh][16384]. Layer 0 fuses the
// input stage (dB -> linear -> tanh). 256 thr (4 waves), 49 KB LDS.
// Phases: stage -> GEMM1(->Sf16) -> reg-scan(->St16 direct) -> GEMM2 -> epi.
// ---------------------------------------------------------------------------
__global__ __launch_bounds__(256, 3)
void k_scan(const float* __restrict__ x, _Float16* __restrict__ u16,
            const _Float16* __restrict__ Wp_all, const _Float16* __restrict__ A2_all,
            const float* __restrict__ wT_all, int layer,
            const float* __restrict__ w_in, const float* __restrict__ b_in) {
    extern __shared__ char smem[];
    char* UT = smem + UT_OFF;            // f16 [128][128] swizzled (byte rows 256)
    char* Sf = smem + SS_OFF;            // f16 [64][136]  (byte rows 272)
    char* St = smem + SS_OFF;            // f16 [128][64] swizzled (byte rows 128)
    char* yst = smem + YST_OFF;          // f16 [128][136] overlay

    const int bh = blockIdx.x;
    const int h  = bh & 63;
    const int tid = threadIdx.x;
    const int lane = tid & 63;
    const int wave = tid >> 6;               // 0..3
    const int ph = layer * 64 + h;
    const _Float16* Wp = Wp_all + (size_t)ph * 8192;
    const _Float16* A2 = A2_all + (size_t)ph * 24576;
    const float* wT4 = wT_all + ph * 128;
    _Float16* uu = u16 + ((size_t)bh << 14);

    const int rA = lane & 15;     // fragment row/col index
    const int qA = lane >> 4;     // fragment k-group

    // ---- stage -> UT (fp16), XOR-swizzled: UT[n][k] at n*256 + (2k ^ ((n&7)<<4))
    if (layer == 0) {
        const float* xb = x + ((size_t)(bh >> 6) << 14);
        const float wi = w_in[h], bi = b_in[h];
        for (int it = 0; it < 8; ++it) {
            int flat8 = (it * 256 + tid) * 8;
            int n = flat8 >> 7, k = flat8 & 127;
            float4 a = *(const float4*)(xb + flat8);
            float4 b = *(const float4*)(xb + flat8 + 4);
            float f[8] = {a.x, a.y, a.z, a.w, b.x, b.y, b.z, b.w};
            f16x8 hv;
            #pragma unroll
            for (int j = 0; j < 8; j++) {
                float s = 6.0205999132796239f * __log2f(fabsf(f[j]) + 1e-5f);
                hv[j] = (_Float16)fast_tanh(fmaf(s, wi, bi));
            }
            *(f16x8*)(UT + n * 256 + ((k * 2) ^ ((n & 7) << 4))) = hv;
        }
    } else {
        for (int it = 0; it < 8; ++it) {
            int flat8 = (it * 256 + tid) * 8;
            int n = flat8 >> 7, k = flat8 & 127;
            f16x8 hv = *(const f16x8*)(uu + flat8);
            *(f16x8*)(UT + n * 256 + ((k * 2) ^ ((n & 7) << 4))) = hv;
        }
    }
    __syncthreads();

    // ---- GEMM1: Sf16[64 moderow][128 chunk] = Wp . U  (4 waves x 1 m-tile) ----
    {
        f32x4 acc1[8];
        #pragma unroll
        for (int nt = 0; nt < 8; nt++) acc1[nt] = (f32x4){0.f, 0.f, 0.f, 0.f};
        for (int ks = 0; ks < 4; ks++) {
            f16x8 af = *(const f16x8*)(Wp + (wave * 16 + rA) * 128 + ks * 32 + qA * 8);
            #pragma unroll
            for (int nt = 0; nt < 8; nt++) {
                int n = nt * 16 + rA;
                f16x8 bv = *(const f16x8*)(UT + n * 256 + ((ks * 64 + qA * 16) ^ ((n & 7) << 4)));
                acc1[nt] = MFMA16F(af, bv, acc1[nt]);
            }
        }
        #pragma unroll
        for (int nt = 0; nt < 8; nt++) {
            int c = nt * 16 + rA;
            #pragma unroll
            for (int r = 0; r < 4; r++)
                *(_Float16*)(Sf + (wave * 16 + qA * 4 + r) * 272 + c * 2) = (_Float16)acc1[nt][r];
        }
    }
    __syncthreads();

    // ---- cross-chunk scan: Sf16 -> registers -> St16 (direct, fp16) ----
    {
        const int sn = tid >> 3;        // mode 0..31
        const int ss = tid & 7;         // sub-block of 16 chunks
        const float wTr = wT4[sn * 4 + 0], wTi = wT4[sn * 4 + 1];
        float fr[16], fi[16];
        {
            f16x8 a0 = *(const f16x8*)(Sf + sn * 272 + ss * 32);
            f16x8 a1 = *(const f16x8*)(Sf + sn * 272 + ss * 32 + 16);
            f16x8 b0 = *(const f16x8*)(Sf + (sn + 32) * 272 + ss * 32);
            f16x8 b1 = *(const f16x8*)(Sf + (sn + 32) * 272 + ss * 32 + 16);
            #pragma unroll
            for (int j = 0; j < 8; j++) {
                fr[j] = (float)a0[j]; fr[j + 8] = (float)a1[j];
                fi[j] = (float)b0[j]; fi[j + 8] = (float)b1[j];
            }
        }
        // sub-block total
        float Tr = 0.f, Ti = 0.f;
        #pragma unroll
        for (int i = 0; i < 16; i++) {
            float nTr = fmaf(wTr, Tr, fmaf(-wTi, Ti, fr[i]));
            Ti = fmaf(wTr, Ti, fmaf(wTi, Tr, fi[i]));
            Tr = nTr;
        }
        // Kogge-Stone over 8 sub-blocks, decay wT^16 squared per step
        float gr = wT4[sn * 4 + 2], gi = wT4[sn * 4 + 3];
        #pragma unroll
        for (int s = 0; s < 3; s++) {
            float pr = __shfl_up(Tr, 1 << s, 8);
            float pi = __shfl_up(Ti, 1 << s, 8);
            if (ss >= (1 << s)) {
                Tr = fmaf(gr, pr, fmaf(-gi, pi, Tr));
                Ti = fmaf(gr, pi, fmaf(gi, pr, Ti));
            }
            float ngr = fmaf(gr, gr, -gi * gi);
            gi = 2.f * gr * gi; gr = ngr;
        }
        float Er_ = __shfl_up(Tr, 1, 8);
        float Ei_ = __shfl_up(Ti, 1, 8);
        if (ss == 0) { Er_ = 0.f; Ei_ = 0.f; }
        __syncthreads();   // all Sf reads done; St overlays Sf
        // replay: write init states (fp16) directly, swizzled for B-fragments
        float Gr = Er_, Gi = Ei_;
        #pragma unroll
        for (int i = 0; i < 16; i++) {
            int c = ss * 16 + i;
            int sw = (c & 7) << 4;
            *(_Float16*)(St + c * 128 + ((sn * 2) ^ sw))        = (_Float16)Gr;
            *(_Float16*)(St + c * 128 + (((sn + 32) * 2) ^ sw)) = (_Float16)Gi;
            float nGr = fmaf(wTr, Gr, fmaf(-wTi, Gi, fr[i]));
            Gi = fmaf(wTr, Gi, fmaf(wTi, Gr, fi[i]));
            Gr = nGr;
        }
    }
    __syncthreads();

    // ---- GEMM2: Y[128 m][128 c] = Ktoe.U (K=128) + E.S (K=64) ----
    f32x4 acc[2][8];
    #pragma unroll
    for (int mi = 0; mi < 2; mi++)
        #pragma unroll
        for (int nt = 0; nt < 8; nt++) acc[mi][nt] = (f32x4){0.f, 0.f, 0.f, 0.f};
    #pragma unroll
    for (int mi = 0; mi < 2; mi++) {
        const _Float16* Arow = A2 + ((wave * 2 + mi) * 16 + rA) * 192;
        for (int ks = 0; ks < 4; ks++) {
            f16x8 af = *(const f16x8*)(Arow + ks * 32 + qA * 8);
            #pragma unroll
            for (int nt = 0; nt < 8; nt++) {
                int n = nt * 16 + rA;
                f16x8 bv = *(const f16x8*)(UT + n * 256 + ((ks * 64 + qA * 16) ^ ((n & 7) << 4)));
                acc[mi][nt] = MFMA16F(af, bv, acc[mi][nt]);
            }
        }
        #pragma unroll
        for (int ks2 = 0; ks2 < 2; ks2++) {
            f16x8 af = *(const f16x8*)(Arow + 128 + ks2 * 32 + qA * 8);
            #pragma unroll
            for (int nt = 0; nt < 8; nt++) {
                int c = nt * 16 + rA;
                f16x8 bv = *(const f16x8*)(St + c * 128 + ((ks2 * 64 + qA * 16) ^ ((c & 7) << 4)));
                acc[mi][nt] = MFMA16F(af, bv, acc[mi][nt]);
            }
        }
    }
    __syncthreads();   // all UT/St reads done; yst overlays

    // ---- epilogue: tanh -> yst fp16 [c][m], then coalesced f16x8 store ----
    #pragma unroll
    for (int mi = 0; mi < 2; mi++) {
        int m0 = (wave * 2 + mi) * 16 + qA * 4;
        #pragma unroll
        for (int nt = 0; nt < 8; nt++) {
            int c = nt * 16 + rA;
            f16x4 o;
            o[0] = (_Float16)fast_tanh(acc[mi][nt][0]);
            o[1] = (_Float16)fast_tanh(acc[mi][nt][1]);
            o[2] = (_Float16)fast_tanh(acc[mi][nt][2]);
            o[3] = (_Float16)fast_tanh(acc[mi][nt][3]);
            *(f16x4*)(yst + c * 272 + m0 * 2) = o;
        }
    }
    __syncthreads();
    for (int it = 0; it < 8; ++it) {
        int e = it * 256 + tid;      // 0..2047
        int c = e >> 4, l8 = e & 15;
        f16x8 hv = *(const f16x8*)(yst + c * 272 + l8 * 16);
        *(f16x8*)(uu + c * 128 + l8 * 8) = hv;
    }
}

// ---------------------------------------------------------------------------
// k_linear: MFMA channel-mix + tanh, fp16 in-place.
// ---------------------------------------------------------------------------
__global__ __launch_bounds__(256, 4)
void k_linear(_Float16* __restrict__ uio, const _Float16* __restrict__ W16,
              const float* __restrict__ bias) {
    __shared__ __align__(16) char lmem[33792];
    _Float16* Ul  = (_Float16*)lmem;     // [256 l][64 h], row 128 B, swizzled
    _Float16* yst = (_Float16*)lmem;     // [64 o][264 l] overlay after GEMM

    const int b   = blockIdx.y;
    const int l0  = blockIdx.x * 256;
    const int tid = threadIdx.x;
    const int lane = tid & 63;
    const int wave = tid >> 6;      // m-tile 0..3
    const int rA = lane & 15;
    const int qA = lane >> 4;

    _Float16* ub = uio + ((size_t)b << 20) + l0;

    for (int it = 0; it < 4; ++it) {
        int g  = it * 256 + tid;
        int hp = g >> 5;
        int l8 = g & 31;
        f16x8 v0 = *(const f16x8*)(ub + (size_t)(hp * 2)     * Lq + l8 * 8);
        f16x8 v1 = *(const f16x8*)(ub + (size_t)(hp * 2 + 1) * Lq + l8 * 8);
        const unsigned short* p0 = (const unsigned short*)&v0;
        const unsigned short* p1 = (const unsigned short*)&v1;
        int sw = (l8 & 7) << 4;
        #pragma unroll
        for (int j = 0; j < 8; j++) {
            unsigned int pk = (unsigned int)p0[j] | ((unsigned int)p1[j] << 16);
            *(unsigned int*)((char*)Ul + (l8 * 8 + j) * 128 + ((hp * 4) ^ sw)) = pk;
        }
    }
    __syncthreads();

    f32x4 acc[16];
    #pragma unroll
    for (int nt = 0; nt < 16; nt++) acc[nt] = (f32x4){0.f, 0.f, 0.f, 0.f};
    const _Float16* Wrow = W16 + (wave * 16 + rA) * 64;
    #pragma unroll
    for (int kf = 0; kf < 2; kf++) {
        f16x8 af = *(const f16x8*)(Wrow + kf * 32 + qA * 8);
        #pragma unroll
        for (int nt = 0; nt < 16; nt++) {
            int n = nt * 16 + rA;
            int sw = ((n >> 3) & 7) << 4;
            f16x8 bv = *(const f16x8*)((char*)Ul + n * 128 + ((kf * 64 + qA * 16) ^ sw));
            acc[nt] = MFMA16F(af, bv, acc[nt]);
        }
    }
    __syncthreads();

    {
        int ob = wave * 16 + qA * 4;
        float bo0 = bias[ob], bo1 = bias[ob + 1], bo2 = bias[ob + 2], bo3 = bias[ob + 3];
        #pragma unroll
        for (int nt = 0; nt < 16; nt++) {
            int l = nt * 16 + rA;
            yst[(ob + 0) * 264 + l] = (_Float16)fast_tanh(acc[nt][0] + bo0);
            yst[(ob + 1) * 264 + l] = (_Float16)fast_tanh(acc[nt][1] + bo1);
            yst[(ob + 2) * 264 + l] = (_Float16)fast_tanh(acc[nt][2] + bo2);
            yst[(ob + 3) * 264 + l] = (_Float16)fast_tanh(acc[nt][3] + bo3);
        }
    }
    __syncthreads();
    for (int it = 0; it < 8; ++it) {
        int e = it * 256 + tid;
        int o = e >> 5, l8 = e & 31;
        f16x8 hv = *(const f16x8*)(yst + o * 264 + l8 * 8);
        *(f16x8*)(ub + (size_t)o * Lq + l8 * 8) = hv;
    }
}

// ---------------------------------------------------------------------------
// k_out: out[b,l] = x[b,l] * 10^((sum_h w_out[h]*u16[b,h,l] + b_out)/20)
// ---------------------------------------------------------------------------
__global__ __launch_bounds__(256)
void k_out(const _Float16* __restrict__ u16, const float* __restrict__ x,
           const float* __restrict__ w_out, const float* __restrict__ b_out,
           float* __restrict__ out) {
    int idx = blockIdx.x * 256 + threadIdx.x;
    int b = idx >> 14;
    int l = idx & (Lq - 1);
    const _Float16* up = u16 + ((size_t)b << 20) + l;
    float acc = 0.f;
    #pragma unroll 8
    for (int hh = 0; hh < 64; ++hh)
        acc = fmaf(w_out[hh], (float)up[(size_t)hh << 14], acc);
    float g = acc + b_out[0];
    out[idx] = x[idx] * exp2f(g * 0.16609640474436812f);
}

// ---------------------------------------------------------------------------
extern "C" void kernel_launch(void* const* d_in, const int* in_sizes, int n_in,
                              void* d_out, int out_size, void* d_ws, size_t ws_size,
                              hipStream_t stream) {
    const float* x          = (const float*)d_in[0];
    const float* w_in       = (const float*)d_in[1];
    const float* b_in       = (const float*)d_in[2];
    const float* w_mid      = (const float*)d_in[3];
    const float* b_mid      = (const float*)d_in[4];
    const float* w_out      = (const float*)d_in[5];
    const float* b_out      = (const float*)d_in[6];
    const float* log_dt     = (const float*)d_in[7];
    const float* log_A_real = (const float*)d_in[8];
    const float* A_imag     = (const float*)d_in[9];
    const float* C_re       = (const float*)d_in[10];
    const float* C_im       = (const float*)d_in[11];
    const float* Dv         = (const float*)d_in[12];

    char* ws = (char*)d_ws;
    float*     wT_tab = (float*)(ws + WT_OFF_B);
    _Float16*  Wp     = (_Float16*)(ws + WP_OFF_B);
    _Float16*  A2     = (_Float16*)(ws + A2_OFF_B);
    _Float16*  W16    = (_Float16*)(ws + W16_OFF_B);
    _Float16*  u16    = (_Float16*)(ws + U_OFF_B);
    float* out = (float*)d_out;

    hipFuncSetAttribute((const void*)k_scan,
                        hipFuncAttributeMaxDynamicSharedMemorySize, SMEM_SZ);

    k_prep<<<NLAYERSq * Hq * 4, 256, 0, stream>>>(log_dt, log_A_real, A_imag,
                                                  C_re, C_im, Dv, w_mid,
                                                  wT_tab, Wp, A2, W16);
    for (int layer = 0; layer < NLAYERSq; layer++) {
        if (layer > 0)
            k_linear<<<dim3(Lq / 256, Bq), 256, 0, stream>>>(
                u16, W16 + (size_t)(layer - 1) * Hq * Hq, b_mid + (size_t)(layer - 1) * Hq);
        k_scan<<<Bq * Hq, 256, SMEM_SZ, stream>>>(x, u16, Wp, A2, wT_tab, layer,
                                                  w_in, b_in);
    }
    k_out<<<(Bq * Lq) / 256, 256, 0, stream>>>(u16, x, w_out, b_out, out);
}